// Round 7
// baseline (239.509 us; speedup 1.0000x reference)
//
#include <hip/hip_runtime.h>
#include <math.h>
#include <stddef.h>

#define NN    4096
#define BATCH 2
#define CD    64
#define KSEL  24
#define RAD2  0.2025f     // 0.45^2
#define NBINS 256
#define KBASE 1888        // (118<<4): d2 in [2^-9, 2^7) keyed by float bits>>19
#define CCAP  128
#define LCAP  255         // fits uint8 index (+1 encoding)

typedef float f4v __attribute__((ext_vector_type(4)));

__device__ __forceinline__ int d2key(unsigned bits) {
  int k = (int)(bits >> 19) - KBASE;
  return k < 0 ? 0 : (k > NBINS - 1 ? NBINS - 1 : k);
}

// ---- prep: transpose td & sd to (B,N,C); addj = clamp(log tgt_match,-20) - 0.1*tu ----
__global__ __launch_bounds__(256)
void prep_all(const float* __restrict__ td, const float* __restrict__ sd,
              const float* __restrict__ tml, const float* __restrict__ tu,
              float* __restrict__ tdT, float* __restrict__ sdT,
              float* __restrict__ addj) {
  __shared__ float tile[64][65];
  int blk = blockIdx.x;
  if (blk < 256) {
    const float* src = (blk < 128) ? td  : sd;
    float*       dst = (blk < 128) ? tdT : sdT;
    int lb = blk & 127;
    int b  = lb >> 6;
    int j0 = (lb & 63) << 6;
    int jl = threadIdx.x & 63;
    int cq = threadIdx.x >> 6;
    const float* srcp = src + (size_t)b * CD * NN;
#pragma unroll
    for (int r = 0; r < 16; ++r) {
      int c = r * 4 + cq;
      tile[c][jl] = srcp[(size_t)c * NN + j0 + jl];
    }
    __syncthreads();
    float* dstp = dst + (size_t)b * NN * CD;
#pragma unroll
    for (int r = 0; r < 16; ++r) {
      int j = r * 4 + cq;
      dstp[(size_t)(j0 + j) * CD + jl] = tile[jl][j];
    }
  } else {
    int idx = (blk - 256) * 256 + threadIdx.x;
    if (idx < BATCH * NN) {
      int b = idx >> 12, j = idx & (NN - 1);
      float l0 = tml[(size_t)b * 2 * NN + j];
      float l1 = tml[(size_t)b * 2 * NN + NN + j];
      float x  = l1 - l0;
      float sp = fmaxf(x, 0.0f) + log1pf(expf(-fabsf(x)));
      addj[idx] = fmaxf(-sp, -20.0f) - 0.1f * tu[idx];
    }
  }
}

// ---- main: 2 rows per block; per-wave-redundant selection/softmax; 5 barriers total ----
__global__ __launch_bounds__(256, 8)
void matcher_main(const float* __restrict__ sc, const float* __restrict__ tc,
                  const float* __restrict__ sd, const float* __restrict__ td,
                  const float* __restrict__ tdT, const float* __restrict__ sdT,
                  const float* __restrict__ addj,
                  const float* __restrict__ tml, const float* __restrict__ tu,
                  const float* __restrict__ sml,
                  float* __restrict__ oexp, float* __restrict__ odisp,
                  float* __restrict__ oprob, float* __restrict__ oconf,
                  float* __restrict__ oent, float* __restrict__ osrc) {
  __shared__ __align__(16) unsigned idxb[2][NN / 4];   // 8 KB: per-j byte -> list idx+1
  __shared__ __align__(16) int      hist[2][2][NBINS]; // 4 KB: [row][copy][bin]
  __shared__ __align__(16) float4   sdp4[2][CD / 4];   // 512 B
  __shared__ int2     jl[2][LCAP];                     // ~4 KB
  __shared__ float    vlist[2][256];                   // 2 KB (raw scores)
  __shared__ unsigned cand[2][CCAP];                   // 1 KB
  __shared__ int      candn[2], lcount[2];

  const int tid  = threadIdx.x;
  const int w    = tid >> 6;
  const int lane = tid & 63;
  const int row0 = blockIdx.x * 2;
  const int b    = row0 >> 12;
  const int i0   = row0 & (NN - 1);
  const int i1   = i0 + 1;                            // same batch (NN even)

  // ---- init ----
  ((int4*)hist)[tid] = make_int4(0, 0, 0, 0);
  ((int4*)idxb)[tid]       = make_int4(0, 0, 0, 0);
  ((int4*)idxb)[tid + 256] = make_int4(0, 0, 0, 0);
  if (tid < 2) { candn[tid] = 0; lcount[tid] = 0; }
  if (sdT) {
    if (tid < 32) {
      int r = tid >> 4, t = tid & 15;
      sdp4[r][t] = ((const float4*)(sdT + ((size_t)b * NN + (i0 + r)) * CD))[t];
    }
  } else if (tid < 128) {
    int r = tid >> 6, c = tid & 63;
    ((float*)sdp4[r])[c] = sd[(size_t)b * CD * NN + (size_t)c * NN + i0 + r];
  }
  const float* scb = sc + (size_t)b * 3 * NN;
  const float sA0 = scb[i0], sA1 = scb[NN + i0], sA2 = scb[2 * NN + i0];
  const float sB0 = scb[i1], sB1 = scb[NN + i1], sB2 = scb[2 * NN + i1];
  const float4* tcx = (const float4*)(tc + (size_t)b * 3 * NN);
  const float4* tcy = tcx + NN / 4;
  const float4* tcz = tcy + NN / 4;
  __syncthreads();                                    // barrier 1

  // ---- phase 1: one tc sweep -> d2 for BOTH rows (regs) + 2-copy histograms ----
  unsigned dA[16], dB[16];
  const int cp = w >> 1;
#pragma unroll
  for (int k = 0; k < 4; ++k) {
    int g = (k << 8) + tid;
    float4 X = tcx[g], Y = tcy[g], Z = tcz[g];
    float xs[4] = {X.x, X.y, X.z, X.w};
    float ys[4] = {Y.x, Y.y, Y.z, Y.w};
    float zs[4] = {Z.x, Z.y, Z.z, Z.w};
#pragma unroll
    for (int r = 0; r < 4; ++r) {
      float dx = xs[r] - sA0, dy = ys[r] - sA1, dz = zs[r] - sA2;
      float d2 = fmaxf(__fmaf_rn(dx, dx, __fmaf_rn(dy, dy, dz * dz)), 1e-12f);
      unsigned ba = __float_as_uint(d2);
      dA[(k << 2) + r] = ba;
      atomicAdd(&hist[0][cp][d2key(ba)], 1);
      dx = xs[r] - sB0; dy = ys[r] - sB1; dz = zs[r] - sB2;
      d2 = fmaxf(__fmaf_rn(dx, dx, __fmaf_rn(dy, dy, dz * dz)), 1e-12f);
      unsigned bb = __float_as_uint(d2);
      dB[(k << 2) + r] = bb;
      atomicAdd(&hist[1][cp][d2key(bb)], 1);
    }
  }
  __syncthreads();                                    // barrier 2

  // ---- phase 2: per-wave redundant scan -> boundary bin per row ----
  int Bs[2], cbv[2];
#pragma unroll
  for (int rw = 0; rw < 2; ++rw) {
    int4 h0 = ((int4*)hist[rw][0])[lane];
    int4 h1 = ((int4*)hist[rw][1])[lane];
    int tt[4] = {h0.x + h1.x, h0.y + h1.y, h0.z + h1.z, h0.w + h1.w};
    int s = tt[0] + tt[1] + tt[2] + tt[3];
    int inc = s;
#pragma unroll
    for (int off = 1; off < 64; off <<= 1) {
      int q = __shfl_up(inc, off);
      if (lane >= off) inc += q;
    }
    int below = inc - s;
    int Bl = -1, Bb = 0;
#pragma unroll
    for (int q = 0; q < 4; ++q) {
      if (Bl < 0 && below < KSEL && below + tt[q] >= KSEL) { Bl = 4 * lane + q; Bb = below; }
      below += tt[q];
    }
    unsigned long long mk = __ballot(Bl >= 0);
    int sl = __ffsll(mk) - 1;
    Bs[rw]  = __shfl(Bl, sl);
    cbv[rw] = __shfl(Bb, sl);
  }
  // candidate collect (distributed over threads' own regs)
#pragma unroll
  for (int m = 0; m < 16; ++m) {
    if (d2key(dA[m]) == Bs[0]) { int c = atomicAdd(&candn[0], 1); if (c < CCAP) cand[0][c] = dA[m]; }
    if (d2key(dB[m]) == Bs[1]) { int c = atomicAdd(&candn[1], 1); if (c < CCAP) cand[1][c] = dB[m]; }
  }
  __syncthreads();                                    // barrier 3

  // ---- phase 3: per-wave redundant exact rank -> threshold per row ----
  unsigned thrb[2];
#pragma unroll
  for (int rw = 0; rw < 2; ++rw) {
    int nc = candn[rw]; nc = nc < CCAP ? nc : CCAP;
    int Krem = KSEL - cbv[rw];
    int found = 0; unsigned fv = 0;
    for (int e = lane; e < nc; e += 64) {
      unsigned v = cand[rw][e];
      int lt = 0, le = 0;
      for (int m = 0; m < nc; ++m) { unsigned u = cand[rw][m]; lt += (u < v); le += (u <= v); }
      if (lt < Krem && le >= Krem) { found = 1; fv = v; }
    }
    unsigned long long mk = __ballot(found != 0);
    int sl = __ffsll(mk) - 1;
    unsigned d24 = (unsigned)__shfl((int)fv, sl);
    thrb[rw] = __float_as_uint(fmaxf(__uint_as_float(d24), RAD2));
  }

  // ---- phase 4: compact allowed; record byte index per j ----
#pragma unroll
  for (int m = 0; m < 16; ++m) {
    int j = ((m >> 2) << 10) + (tid << 2) + (m & 3);
    if (dA[m] <= thrb[0]) {
      int idx = atomicAdd(&lcount[0], 1);
      if (idx < LCAP) { ((unsigned char*)idxb[0])[j] = (unsigned char)(idx + 1);
                        jl[0][idx] = make_int2(j, (int)dA[m]); }
    }
    if (dB[m] <= thrb[1]) {
      int idx = atomicAdd(&lcount[1], 1);
      if (idx < LCAP) { ((unsigned char*)idxb[1])[j] = (unsigned char)(idx + 1);
                        jl[1][idx] = make_int2(j, (int)dB[m]); }
    }
  }
  __syncthreads();                                    // barrier 4
  int na[2];
  na[0] = lcount[0] < LCAP ? lcount[0] : LCAP;
  na[1] = lcount[1] < LCAP ? lcount[1] : LCAP;

  // ---- phase 5: scores (thread tid owns entry tid of each row) ----
  const float* tdb = tdT ? tdT + (size_t)b * NN * CD : nullptr;
#pragma unroll
  for (int rw = 0; rw < 2; ++rw) {
    if (tid < na[rw]) {
      int2 en = jl[rw][tid];
      int j = en.x;
      float d2 = __uint_as_float((unsigned)en.y);
      const float4* sp4 = (const float4*)sdp4[rw];
      float a0 = 0.f, a1 = 0.f, a2 = 0.f, a3 = 0.f;
      if (tdb) {
        const float4* trow = (const float4*)(tdb + (size_t)j * CD);
#pragma unroll
        for (int q = 0; q < CD / 4; q += 4) {
          float4 x0 = sp4[q],     t0 = trow[q];
          float4 x1 = sp4[q + 1], t1 = trow[q + 1];
          float4 x2 = sp4[q + 2], t2 = trow[q + 2];
          float4 x3 = sp4[q + 3], t3 = trow[q + 3];
          a0 = fmaf(x0.x, t0.x, fmaf(x0.y, t0.y, fmaf(x0.z, t0.z, fmaf(x0.w, t0.w, a0))));
          a1 = fmaf(x1.x, t1.x, fmaf(x1.y, t1.y, fmaf(x1.z, t1.z, fmaf(x1.w, t1.w, a1))));
          a2 = fmaf(x2.x, t2.x, fmaf(x2.y, t2.y, fmaf(x2.z, t2.z, fmaf(x2.w, t2.w, a2))));
          a3 = fmaf(x3.x, t3.x, fmaf(x3.y, t3.y, fmaf(x3.z, t3.z, fmaf(x3.w, t3.w, a3))));
        }
      } else {
        const float* spx = (const float*)sdp4[rw];
        const float* tp  = td + (size_t)b * CD * NN + j;
#pragma unroll 8
        for (int c2 = 0; c2 < CD; ++c2) a0 = fmaf(spx[c2], tp[(size_t)c2 * NN], a0);
      }
      float sim = (a0 + a1) + (a2 + a3);
      float aj;
      if (addj) {
        aj = addj[(size_t)b * NN + j];
      } else {
        float l0 = tml[(size_t)b * 2 * NN + j];
        float l1 = tml[(size_t)b * 2 * NN + NN + j];
        float x  = l1 - l0;
        float sp = fmaxf(x, 0.0f) + log1pf(expf(-fabsf(x)));
        aj = fmaxf(-sp, -20.0f) - 0.1f * tu[(size_t)b * NN + j];
      }
      vlist[rw][tid] = sim - sqrtf(d2) + aj;
    }
  }
  __syncthreads();                                    // barrier 5 (last)

  // ---- phase 6: per-wave redundant softmax + fused stats (no cross-wave reduce) ----
  const float C1   = (1.0f / 0.07f) * 1.44269504089f; // log2(e)/TEMP
  const float STEP = 2.0f / 15.0f;
  const float LN2  = 0.69314718056f;
  float mx[2], invZ[2], st0[2], st1[2], st2[2], stE[2], stC[2];
#pragma unroll
  for (int rw = 0; rw < 2; ++rw) {
    float m_ = -1e30f;
    for (int e = lane; e < na[rw]; e += 64) m_ = fmaxf(m_, vlist[rw][e]);
#pragma unroll
    for (int off = 32; off; off >>= 1) m_ = fmaxf(m_, __shfl_xor(m_, off));
    float zl = 0.f, eu = 0.f, em = 0.f, e0 = 0.f, e1 = 0.f, e2 = 0.f;
    for (int e = lane; e < na[rw]; e += 64) {
      float u  = (vlist[rw][e] - m_) * C1;
      float ev = exp2f(u);
      int j = jl[rw][e].x;
      float pz = -1.0f + STEP * (float)(j >> 8);
      float py = -1.0f + STEP * (float)((j >> 4) & 15);
      float px = -1.0f + STEP * (float)(j & 15);
      zl += ev; eu = fmaf(ev, u, eu); em = fmaxf(em, ev);
      e0 = fmaf(ev, pz, e0); e1 = fmaf(ev, py, e1); e2 = fmaf(ev, px, e2);
    }
#pragma unroll
    for (int off = 32; off; off >>= 1) {
      zl += __shfl_xor(zl, off); eu += __shfl_xor(eu, off);
      em  = fmaxf(em, __shfl_xor(em, off));
      e0 += __shfl_xor(e0, off); e1 += __shfl_xor(e1, off); e2 += __shfl_xor(e2, off);
    }
    float iz = 1.0f / zl;
    mx[rw] = m_; invZ[rw] = iz;
    st0[rw] = e0 * iz; st1[rw] = e1 * iz; st2[rw] = e2 * iz;
    stE[rw] = LN2 * (log2f(zl) - eu * iz);
    stC[rw] = em * iz;
  }

  // ---- phase 7: expand + NT row writes (reads only pre-barrier-5 LDS) ----
#pragma unroll
  for (int q = 0; q < 4; ++q) {
    int c = (q << 8) + tid;
#pragma unroll
    for (int rw = 0; rw < 2; ++rw) {
      unsigned pk = idxb[rw][c];
      f4v v; v[0] = 0.f; v[1] = 0.f; v[2] = 0.f; v[3] = 0.f;
      if (pk) {
#pragma unroll
        for (int r = 0; r < 4; ++r) {
          unsigned u8 = (pk >> (8 * r)) & 0xFFu;
          if (u8) v[r] = exp2f((vlist[rw][u8 - 1] - mx[rw]) * C1) * invZ[rw];
        }
      }
      __builtin_nontemporal_store(v, &((f4v*)(oprob + (size_t)(row0 + rw) * NN))[c]);
    }
  }

  // ---- epilogue: thread 0 has full stats for both rows ----
  if (tid == 0) {
#pragma unroll
    for (int rw = 0; rw < 2; ++rw) {
      int i_ = i0 + rw, row = row0 + rw;
      float tz = -1.0f + STEP * (float)(i_ >> 8);
      float ty = -1.0f + STEP * (float)((i_ >> 4) & 15);
      float tx = -1.0f + STEP * (float)(i_ & 15);
      size_t r3 = (size_t)row * 3;
      oexp[r3 + 0] = st0[rw]; oexp[r3 + 1] = st1[rw]; oexp[r3 + 2] = st2[rw];
      osrc[r3 + 0] = tz; osrc[r3 + 1] = ty; osrc[r3 + 2] = tx;
      size_t db = (size_t)b * 3 * NN;
      odisp[db + 0 * NN + i_] = st0[rw] - tz;
      odisp[db + 1 * NN + i_] = st1[rw] - ty;
      odisp[db + 2 * NN + i_] = st2[rw] - tx;
      float ls0 = sml[(size_t)b * 2 * NN + i_];
      float ls1 = sml[(size_t)b * 2 * NN + NN + i_];
      float smv = 1.0f / (1.0f + expf(ls1 - ls0));
      oconf[(size_t)b * NN + i_] = stC[rw] * smv;
      oent[(size_t)b * NN + i_]  = stE[rw];
    }
  }
}

extern "C" void kernel_launch(void* const* d_in, const int* in_sizes, int n_in,
                              void* d_out, int out_size, void* d_ws, size_t ws_size,
                              hipStream_t stream) {
  const float* sc  = (const float*)d_in[0];
  const float* tc  = (const float*)d_in[1];
  const float* sd  = (const float*)d_in[2];
  const float* td  = (const float*)d_in[3];
  const float* sml = (const float*)d_in[4];
  const float* tml = (const float*)d_in[5];
  const float* tu  = (const float*)d_in[7];
  // src_unc (d_in[6]) cancels in the row softmax -> unused

  float* out   = (float*)d_out;
  float* oexp  = out;
  float* odisp = oexp  + (size_t)BATCH * NN * 3;
  float* oprob = odisp + (size_t)BATCH * NN * 3;
  float* oconf = oprob + (size_t)BATCH * NN * NN;
  float* oent  = oconf + (size_t)BATCH * NN;
  float* osrc  = oent  + (size_t)BATCH * NN;

  size_t need = ((size_t)2 * BATCH * NN * CD + (size_t)BATCH * NN) * sizeof(float);
  float* tdT = nullptr; float* sdT = nullptr; float* adj = nullptr;
  if (ws_size >= need) {
    tdT = (float*)d_ws;
    sdT = tdT + (size_t)BATCH * NN * CD;
    adj = sdT + (size_t)BATCH * NN * CD;
    prep_all<<<256 + 32, 256, 0, stream>>>(td, sd, tml, tu, tdT, sdT, adj);
  }
  matcher_main<<<BATCH * NN / 2, 256, 0, stream>>>(sc, tc, sd, td, tdT, sdT, adj,
                                                   tml, tu, sml,
                                                   oexp, odisp, oprob, oconf, oent, osrc);
}

// Round 8
// 207.396 us; speedup vs baseline: 1.1548x; 1.1548x over previous
//
#include <hip/hip_runtime.h>
#include <math.h>
#include <stddef.h>

#define NN    4096
#define BATCH 2
#define CD    64
#define KSEL  24
#define RAD2  0.2025f     // 0.45^2
#define NBINS 256
#define KBASE 1888        // (118<<4): log bins, d2 in [2^-9, 2^7) via float bits>>19
#define LCAP  255         // fits uint8 index (+1 encoding)

typedef float f4v __attribute__((ext_vector_type(4)));

__device__ __forceinline__ int d2key(unsigned bits) {
  int k = (int)(bits >> 19) - KBASE;
  return k < 0 ? 0 : (k > NBINS - 1 ? NBINS - 1 : k);
}

// per-wave redundant: scan 2-copy 256-bin histogram, return first bin with cum>=KSEL (or -1)
__device__ __forceinline__ int wave_bin24(const int* h0, const int* h1, int lane) {
  int4 a = ((const int4*)h0)[lane];
  int4 b = ((const int4*)h1)[lane];
  int tt[4] = {a.x + b.x, a.y + b.y, a.z + b.z, a.w + b.w};
  int s = tt[0] + tt[1] + tt[2] + tt[3];
  int inc = s;
#pragma unroll
  for (int off = 1; off < 64; off <<= 1) {
    int t = __shfl_up(inc, off);
    if (lane >= off) inc += t;
  }
  int below = inc - s;
  int Bl = -1;
#pragma unroll
  for (int q = 0; q < 4; ++q) {
    if (Bl < 0 && below < KSEL && below + tt[q] >= KSEL) Bl = 4 * lane + q;
    below += tt[q];
  }
  unsigned long long mk = __ballot(Bl >= 0);
  if (!mk) return -1;
  return __shfl(Bl, __ffsll((long long)mk) - 1);
}

// ---- prep: transpose td & sd to (B,N,C); addj = clamp(log tgt_match,-20) - 0.1*tu ----
__global__ __launch_bounds__(256)
void prep_all(const float* __restrict__ td, const float* __restrict__ sd,
              const float* __restrict__ tml, const float* __restrict__ tu,
              float* __restrict__ tdT, float* __restrict__ sdT,
              float* __restrict__ addj) {
  __shared__ float tile[64][65];
  int blk = blockIdx.x;
  if (blk < 256) {
    const float* src = (blk < 128) ? td  : sd;
    float*       dst = (blk < 128) ? tdT : sdT;
    int lb = blk & 127;
    int b  = lb >> 6;
    int j0 = (lb & 63) << 6;
    int jl = threadIdx.x & 63;
    int cq = threadIdx.x >> 6;
    const float* srcp = src + (size_t)b * CD * NN;
#pragma unroll
    for (int r = 0; r < 16; ++r) {
      int c = r * 4 + cq;
      tile[c][jl] = srcp[(size_t)c * NN + j0 + jl];
    }
    __syncthreads();
    float* dstp = dst + (size_t)b * NN * CD;
#pragma unroll
    for (int r = 0; r < 16; ++r) {
      int j = r * 4 + cq;
      dstp[(size_t)(j0 + j) * CD + jl] = tile[jl][j];
    }
  } else {
    int idx = (blk - 256) * 256 + threadIdx.x;
    if (idx < BATCH * NN) {
      int b = idx >> 12, j = idx & (NN - 1);
      float l0 = tml[(size_t)b * 2 * NN + j];
      float l1 = tml[(size_t)b * 2 * NN + NN + j];
      float x  = l1 - l0;
      float sp = fmaxf(x, 0.0f) + log1pf(expf(-fabsf(x)));
      addj[idx] = fmaxf(-sp, -20.0f) - 0.1f * tu[idx];
    }
  }
}

// ---- main: 1 row/block, 4 barriers, conditional histogram, list-domain selection ----
__global__ __launch_bounds__(256, 8)
void matcher_main(const float* __restrict__ sc, const float* __restrict__ tc,
                  const float* __restrict__ sd, const float* __restrict__ td,
                  const float* __restrict__ tdT, const float* __restrict__ sdT,
                  const float* __restrict__ addj,
                  const float* __restrict__ tml, const float* __restrict__ tu,
                  const float* __restrict__ sml,
                  float* __restrict__ oexp, float* __restrict__ odisp,
                  float* __restrict__ oprob, float* __restrict__ oconf,
                  float* __restrict__ oent, float* __restrict__ osrc) {
  __shared__ __align__(16) unsigned idxb[NN / 4];   // 4 KB: per-j byte -> list idx+1
  __shared__ __align__(16) int      hist[2][NBINS]; // 2 KB, 2 copies
  __shared__ __align__(16) float4   sdp4[CD / 4];
  __shared__ int2  lst[LCAP];                       // (j, d2bits) then (j, unused)
  __shared__ float vlist[256];                      // raw scores
  __shared__ int   lcount;

  const int tid  = threadIdx.x;
  const int w    = tid >> 6;
  const int lane = tid & 63;
  const int row  = blockIdx.x;
  const int b    = row >> 12;
  const int i    = row & (NN - 1);
  const unsigned RADB = __float_as_uint(RAD2);

  // ---- init ----
  if (tid < 128) ((int4*)hist)[tid] = make_int4(0, 0, 0, 0);
#pragma unroll
  for (int q = 0; q < 4; ++q) idxb[(q << 8) + tid] = 0u;
  if (sdT) { if (tid < 16) sdp4[tid] = ((const float4*)(sdT + ((size_t)b * NN + i) * CD))[tid]; }
  else     { if (tid < 64) ((float*)sdp4)[tid] = sd[(size_t)b * CD * NN + (size_t)tid * NN + i]; }
  if (tid == 0) lcount = 0;

  const float* scb = sc + (size_t)b * 3 * NN;
  const float s0 = scb[i], s1 = scb[NN + i], s2 = scb[2 * NN + i];
  const float4* tcx = (const float4*)(tc + (size_t)b * 3 * NN);
  const float4* tcy = tcx + NN / 4;
  const float4* tcz = tcy + NN / 4;
  const int cp = w >> 1;
  __syncthreads();                                  // barrier 1

  // ---- phase 1: d2 -> 16 regs; histogram ONLY d2 < 2.0 (~20% of entries) ----
  unsigned d2b[16];
#pragma unroll
  for (int k = 0; k < 4; ++k) {
    int g = (k << 8) + tid;
    float4 X = tcx[g], Y = tcy[g], Z = tcz[g];
    float xs[4] = {X.x, X.y, X.z, X.w};
    float ys[4] = {Y.x, Y.y, Y.z, Y.w};
    float zs[4] = {Z.x, Z.y, Z.z, Z.w};
#pragma unroll
    for (int r = 0; r < 4; ++r) {
      float dx = xs[r] - s0, dy = ys[r] - s1, dz = zs[r] - s2;
      float d2 = fmaxf(__fmaf_rn(dx, dx, __fmaf_rn(dy, dy, dz * dz)), 1e-12f);
      unsigned bits = __float_as_uint(d2);
      d2b[(k << 2) + r] = bits;
      if (d2 < 2.0f) atomicAdd(&hist[cp][d2key(bits)], 1);
    }
  }
  __syncthreads();                                  // barrier 2

  // ---- phase 2: per-wave redundant scan; rare fallback adds the d2>=2 tail ----
  int Bs = wave_bin24(hist[0], hist[1], lane);
  if (Bs < 0) {                                     // <24 within d2<2 — block-uniform, ~1% rows
    __syncthreads();
#pragma unroll
    for (int m = 0; m < 16; ++m)
      if (__uint_as_float(d2b[m]) >= 2.0f) atomicAdd(&hist[cp][d2key(d2b[m])], 1);
    __syncthreads();
    Bs = wave_bin24(hist[0], hist[1], lane);        // total 4096 -> always found
  }

  // ---- phase 3: compact {bin<=Bs || d2<=RAD2}; superset of allowed; byte index map ----
#pragma unroll
  for (int m = 0; m < 16; ++m) {
    unsigned bits = d2b[m];
    if (d2key(bits) <= Bs || bits <= RADB) {
      int idx = atomicAdd(&lcount, 1);
      if (idx < LCAP) {
        int j = ((m >> 2) << 10) + (tid << 2) + (m & 3);
        ((unsigned char*)idxb)[j] = (unsigned char)(idx + 1);
        lst[idx] = make_int2(j, (int)bits);
      }
    }
  }
  __syncthreads();                                  // barrier 3
  const int na = lcount < LCAP ? lcount : LCAP;

  // ---- phase 4: per-wave redundant exact d24 rank inside the list ----
  unsigned thrb;
  {
    int found = 0; unsigned fv = 0;
    for (int e = lane; e < na; e += 64) {
      unsigned v = (unsigned)lst[e].y;
      int lt = 0, le = 0;
      for (int m = 0; m < na; ++m) {
        unsigned u = (unsigned)lst[m].y;
        lt += (u < v); le += (u <= v);
      }
      if (lt < KSEL && le >= KSEL) { found = 1; fv = v; }
    }
    unsigned long long mk = __ballot(found != 0);
    // na>=24 always => some lane found; ties resolved to the same value
    unsigned d24 = (unsigned)__shfl((int)fv, __ffsll((long long)mk) - 1);
    thrb = d24 > RADB ? d24 : RADB;
  }

  // ---- phase 5: scores (thread tid owns list entry tid) ----
  const float* tdb = tdT ? tdT + (size_t)b * NN * CD : nullptr;
  if (tid < na) {
    int2 en = lst[tid];
    int j = en.x;
    unsigned bits = (unsigned)en.y;
    float d2 = __uint_as_float(bits);
    float a0 = 0.f, a1 = 0.f, a2 = 0.f, a3 = 0.f;
    if (tdb) {
      const float4* trow = (const float4*)(tdb + (size_t)j * CD);
#pragma unroll
      for (int q = 0; q < CD / 4; q += 4) {
        float4 x0 = sdp4[q],     t0 = trow[q];
        float4 x1 = sdp4[q + 1], t1 = trow[q + 1];
        float4 x2 = sdp4[q + 2], t2 = trow[q + 2];
        float4 x3 = sdp4[q + 3], t3 = trow[q + 3];
        a0 = fmaf(x0.x, t0.x, fmaf(x0.y, t0.y, fmaf(x0.z, t0.z, fmaf(x0.w, t0.w, a0))));
        a1 = fmaf(x1.x, t1.x, fmaf(x1.y, t1.y, fmaf(x1.z, t1.z, fmaf(x1.w, t1.w, a1))));
        a2 = fmaf(x2.x, t2.x, fmaf(x2.y, t2.y, fmaf(x2.z, t2.z, fmaf(x2.w, t2.w, a2))));
        a3 = fmaf(x3.x, t3.x, fmaf(x3.y, t3.y, fmaf(x3.z, t3.z, fmaf(x3.w, t3.w, a3))));
      }
    } else {
      const float* spx = (const float*)sdp4;
      const float* tp  = td + (size_t)b * CD * NN + j;
#pragma unroll 8
      for (int c2 = 0; c2 < CD; ++c2) a0 = fmaf(spx[c2], tp[(size_t)c2 * NN], a0);
    }
    float sim = (a0 + a1) + (a2 + a3);
    float aj;
    if (addj) {
      aj = addj[(size_t)b * NN + j];
    } else {
      float l0 = tml[(size_t)b * 2 * NN + j];
      float l1 = tml[(size_t)b * 2 * NN + NN + j];
      float x  = l1 - l0;
      float sp = fmaxf(x, 0.0f) + log1pf(expf(-fabsf(x)));
      aj = fmaxf(-sp, -20.0f) - 0.1f * tu[(size_t)b * NN + j];
    }
    // boundary-bin tail beyond the 24th: not allowed -> p must be exactly 0
    vlist[tid] = (bits <= thrb) ? (sim - sqrtf(d2) + aj) : -1e30f;
  }
  __syncthreads();                                  // barrier 4 (last)

  // ---- phase 6: per-wave redundant softmax + fused stats ----
  const float C1   = (1.0f / 0.07f) * 1.44269504089f;  // log2(e)/TEMP
  const float STEP = 2.0f / 15.0f;
  const float LN2  = 0.69314718056f;
  float m_ = -1e30f;
  for (int e = lane; e < na; e += 64) m_ = fmaxf(m_, vlist[e]);
#pragma unroll
  for (int off = 32; off; off >>= 1) m_ = fmaxf(m_, __shfl_xor(m_, off));
  float zl = 0.f, eu = 0.f, em = 0.f, e0 = 0.f, e1 = 0.f, e2 = 0.f;
  for (int e = lane; e < na; e += 64) {
    float u  = (vlist[e] - m_) * C1;
    float ev = exp2f(u);
    int j = lst[e].x;
    float pz = -1.0f + STEP * (float)(j >> 8);
    float py = -1.0f + STEP * (float)((j >> 4) & 15);
    float px = -1.0f + STEP * (float)(j & 15);
    zl += ev; eu = fmaf(ev, u, eu); em = fmaxf(em, ev);
    e0 = fmaf(ev, pz, e0); e1 = fmaf(ev, py, e1); e2 = fmaf(ev, px, e2);
  }
#pragma unroll
  for (int off = 32; off; off >>= 1) {
    zl += __shfl_xor(zl, off); eu += __shfl_xor(eu, off);
    em  = fmaxf(em, __shfl_xor(em, off));
    e0 += __shfl_xor(e0, off); e1 += __shfl_xor(e1, off); e2 += __shfl_xor(e2, off);
  }
  const float invZ = 1.0f / zl;

  // ---- phase 7: expand + NT row write (idxb final since barrier 3, vlist since 4) ----
  f4v* prow4 = (f4v*)(oprob + (size_t)row * NN);
#pragma unroll
  for (int q = 0; q < 4; ++q) {
    int c = (q << 8) + tid;
    unsigned pk = idxb[c];
    f4v v; v[0] = 0.f; v[1] = 0.f; v[2] = 0.f; v[3] = 0.f;
    if (pk) {
#pragma unroll
      for (int r = 0; r < 4; ++r) {
        unsigned u8 = (pk >> (8 * r)) & 0xFFu;
        if (u8) v[r] = exp2f((vlist[u8 - 1] - m_) * C1) * invZ;
      }
    }
    __builtin_nontemporal_store(v, &prow4[c]);
  }

  // ---- epilogue (tid 0 holds wave-0's redundant stats) ----
  if (tid == 0) {
    float p0 = e0 * invZ, p1 = e1 * invZ, p2 = e2 * invZ;
    float ent = LN2 * (log2f(zl) - eu * invZ);
    float tz = -1.0f + STEP * (float)(i >> 8);
    float ty = -1.0f + STEP * (float)((i >> 4) & 15);
    float tx = -1.0f + STEP * (float)(i & 15);
    size_t r3 = (size_t)row * 3;
    oexp[r3 + 0] = p0; oexp[r3 + 1] = p1; oexp[r3 + 2] = p2;
    osrc[r3 + 0] = tz; osrc[r3 + 1] = ty; osrc[r3 + 2] = tx;
    size_t db = (size_t)b * 3 * NN;
    odisp[db + 0 * NN + i] = p0 - tz;
    odisp[db + 1 * NN + i] = p1 - ty;
    odisp[db + 2 * NN + i] = p2 - tx;
    float ls0 = sml[(size_t)b * 2 * NN + i];
    float ls1 = sml[(size_t)b * 2 * NN + NN + i];
    float smv = 1.0f / (1.0f + expf(ls1 - ls0));
    oconf[(size_t)b * NN + i] = (em * invZ) * smv;
    oent[(size_t)b * NN + i]  = ent;
  }
}

extern "C" void kernel_launch(void* const* d_in, const int* in_sizes, int n_in,
                              void* d_out, int out_size, void* d_ws, size_t ws_size,
                              hipStream_t stream) {
  const float* sc  = (const float*)d_in[0];
  const float* tc  = (const float*)d_in[1];
  const float* sd  = (const float*)d_in[2];
  const float* td  = (const float*)d_in[3];
  const float* sml = (const float*)d_in[4];
  const float* tml = (const float*)d_in[5];
  const float* tu  = (const float*)d_in[7];
  // src_unc (d_in[6]) cancels in the row softmax -> unused

  float* out   = (float*)d_out;
  float* oexp  = out;
  float* odisp = oexp  + (size_t)BATCH * NN * 3;
  float* oprob = odisp + (size_t)BATCH * NN * 3;
  float* oconf = oprob + (size_t)BATCH * NN * NN;
  float* oent  = oconf + (size_t)BATCH * NN;
  float* osrc  = oent  + (size_t)BATCH * NN;

  size_t need = ((size_t)2 * BATCH * NN * CD + (size_t)BATCH * NN) * sizeof(float);
  float* tdT = nullptr; float* sdT = nullptr; float* adj = nullptr;
  if (ws_size >= need) {
    tdT = (float*)d_ws;
    sdT = tdT + (size_t)BATCH * NN * CD;
    adj = sdT + (size_t)BATCH * NN * CD;
    prep_all<<<256 + 32, 256, 0, stream>>>(td, sd, tml, tu, tdT, sdT, adj);
  }
  matcher_main<<<BATCH * NN, 256, 0, stream>>>(sc, tc, sd, td, tdT, sdT, adj,
                                               tml, tu, sml,
                                               oexp, odisp, oprob, oconf, oent, osrc);
}

// Round 9
// 194.037 us; speedup vs baseline: 1.2343x; 1.0688x over previous
//
#include <hip/hip_runtime.h>
#include <math.h>
#include <stddef.h>

#define NN    4096
#define BATCH 2
#define CD    64
#define KSEL  24
#define RAD2  0.2025f     // 0.45^2
#define NBINS 256
#define KBASE 1888        // (118<<4): log bins, d2 in [2^-9, 2^7) via float bits>>19
#define LCAP  255         // fits uint8 index (+1 encoding)
#define CCAP  64

typedef float f4v __attribute__((ext_vector_type(4)));

__device__ __forceinline__ int d2key(unsigned bits) {
  int k = (int)(bits >> 19) - KBASE;
  return k < 0 ? 0 : (k > NBINS - 1 ? NBINS - 1 : k);
}

// per-wave redundant: scan 2-copy 256-bin histogram; bin with cum>=KSEL (or -1) + count below
__device__ __forceinline__ int wave_bin24(const int* h0, const int* h1, int lane, int* cb_out) {
  int4 a = ((const int4*)h0)[lane];
  int4 b = ((const int4*)h1)[lane];
  int tt[4] = {a.x + b.x, a.y + b.y, a.z + b.z, a.w + b.w};
  int s = tt[0] + tt[1] + tt[2] + tt[3];
  int inc = s;
#pragma unroll
  for (int off = 1; off < 64; off <<= 1) {
    int t = __shfl_up(inc, off);
    if (lane >= off) inc += t;
  }
  int below = inc - s;
  int Bl = -1, Bb = 0;
#pragma unroll
  for (int q = 0; q < 4; ++q) {
    if (Bl < 0 && below < KSEL && below + tt[q] >= KSEL) { Bl = 4 * lane + q; Bb = below; }
    below += tt[q];
  }
  unsigned long long mk = __ballot(Bl >= 0);
  if (!mk) return -1;
  int sl = __ffsll((long long)mk) - 1;
  *cb_out = __shfl(Bb, sl);
  return __shfl(Bl, sl);
}

// ---- prep: transpose td & sd to (B,N,C); addj = clamp(log tgt_match,-20) - 0.1*tu ----
__global__ __launch_bounds__(256)
void prep_all(const float* __restrict__ td, const float* __restrict__ sd,
              const float* __restrict__ tml, const float* __restrict__ tu,
              float* __restrict__ tdT, float* __restrict__ sdT,
              float* __restrict__ addj) {
  __shared__ float tile[64][65];
  int blk = blockIdx.x;
  if (blk < 256) {
    const float* src = (blk < 128) ? td  : sd;
    float*       dst = (blk < 128) ? tdT : sdT;
    int lb = blk & 127;
    int b  = lb >> 6;
    int j0 = (lb & 63) << 6;
    int jl = threadIdx.x & 63;
    int cq = threadIdx.x >> 6;
    const float* srcp = src + (size_t)b * CD * NN;
#pragma unroll
    for (int r = 0; r < 16; ++r) {
      int c = r * 4 + cq;
      tile[c][jl] = srcp[(size_t)c * NN + j0 + jl];
    }
    __syncthreads();
    float* dstp = dst + (size_t)b * NN * CD;
#pragma unroll
    for (int r = 0; r < 16; ++r) {
      int j = r * 4 + cq;
      dstp[(size_t)(j0 + j) * CD + jl] = tile[jl][j];
    }
  } else {
    int idx = (blk - 256) * 256 + threadIdx.x;
    if (idx < BATCH * NN) {
      int b = idx >> 12, j = idx & (NN - 1);
      float l0 = tml[(size_t)b * 2 * NN + j];
      float l1 = tml[(size_t)b * 2 * NN + NN + j];
      float x  = l1 - l0;
      float sp = fmaxf(x, 0.0f) + log1pf(expf(-fabsf(x)));
      addj[idx] = fmaxf(-sp, -20.0f) - 0.1f * tu[idx];
    }
  }
}

// ---- main: 1 row/block, 4 barriers, boundary-bin rank, packed (j,score) list ----
__global__ __launch_bounds__(256, 8)
void matcher_main(const float* __restrict__ sc, const float* __restrict__ tc,
                  const float* __restrict__ sd, const float* __restrict__ td,
                  const float* __restrict__ tdT, const float* __restrict__ sdT,
                  const float* __restrict__ addj,
                  const float* __restrict__ tml, const float* __restrict__ tu,
                  const float* __restrict__ sml,
                  float* __restrict__ oexp, float* __restrict__ odisp,
                  float* __restrict__ oprob, float* __restrict__ oconf,
                  float* __restrict__ oent, float* __restrict__ osrc) {
  __shared__ __align__(16) unsigned idxb[NN / 4];   // 4 KB: per-j byte -> list idx+1
  __shared__ __align__(16) int      hist[2][NBINS]; // 2 KB, 2 copies
  __shared__ __align__(16) float4   sdp4[CD / 4];
  __shared__ int2     lst[LCAP];                    // (j, d2bits)
  __shared__ int2     slist[256];                   // (j, score bits)
  __shared__ unsigned cand[CCAP];                   // boundary-bin d2bits
  __shared__ int      lcount, candn;

  const int tid  = threadIdx.x;
  const int w    = tid >> 6;
  const int lane = tid & 63;
  const int row  = blockIdx.x;
  const int b    = row >> 12;
  const int i    = row & (NN - 1);
  const unsigned RADB = __float_as_uint(RAD2);

  // ---- init ----
  if (tid < 128) ((int4*)hist)[tid] = make_int4(0, 0, 0, 0);
#pragma unroll
  for (int q = 0; q < 4; ++q) idxb[(q << 8) + tid] = 0u;
  if (sdT) { if (tid < 16) sdp4[tid] = ((const float4*)(sdT + ((size_t)b * NN + i) * CD))[tid]; }
  else     { if (tid < 64) ((float*)sdp4)[tid] = sd[(size_t)b * CD * NN + (size_t)tid * NN + i]; }
  if (tid == 0) { lcount = 0; candn = 0; }

  const float* scb = sc + (size_t)b * 3 * NN;
  const float s0 = scb[i], s1 = scb[NN + i], s2 = scb[2 * NN + i];
  const float4* tcx = (const float4*)(tc + (size_t)b * 3 * NN);
  const float4* tcy = tcx + NN / 4;
  const float4* tcz = tcy + NN / 4;
  const int cp = w >> 1;
  __syncthreads();                                  // barrier 1

  // ---- phase 1: d2 -> 16 regs; histogram ONLY d2 < 2.0 (~20% of entries) ----
  unsigned d2b[16];
#pragma unroll
  for (int k = 0; k < 4; ++k) {
    int g = (k << 8) + tid;
    float4 X = tcx[g], Y = tcy[g], Z = tcz[g];
    float xs[4] = {X.x, X.y, X.z, X.w};
    float ys[4] = {Y.x, Y.y, Y.z, Y.w};
    float zs[4] = {Z.x, Z.y, Z.z, Z.w};
#pragma unroll
    for (int r = 0; r < 4; ++r) {
      float dx = xs[r] - s0, dy = ys[r] - s1, dz = zs[r] - s2;
      float d2 = fmaxf(__fmaf_rn(dx, dx, __fmaf_rn(dy, dy, dz * dz)), 1e-12f);
      unsigned bits = __float_as_uint(d2);
      d2b[(k << 2) + r] = bits;
      if (d2 < 2.0f) atomicAdd(&hist[cp][d2key(bits)], 1);
    }
  }
  __syncthreads();                                  // barrier 2

  // ---- phase 2: per-wave redundant scan; rare fallback adds the d2>=2 tail ----
  int cb = 0;
  int Bs = wave_bin24(hist[0], hist[1], lane, &cb);
  if (Bs < 0) {                                     // <24 within d2<2 — block-uniform, ~1% rows
    __syncthreads();
#pragma unroll
    for (int m = 0; m < 16; ++m)
      if (__uint_as_float(d2b[m]) >= 2.0f) atomicAdd(&hist[cp][d2key(d2b[m])], 1);
    __syncthreads();
    Bs = wave_bin24(hist[0], hist[1], lane, &cb);   // total 4096 -> always found
  }

  // ---- phase 3: compact {bin<=Bs || d2<=RAD2}; boundary-bin bits also into cand ----
#pragma unroll
  for (int m = 0; m < 16; ++m) {
    unsigned bits = d2b[m];
    int key = d2key(bits);
    if (key <= Bs || bits <= RADB) {
      int idx = atomicAdd(&lcount, 1);
      if (idx < LCAP) {
        int j = ((m >> 2) << 10) + (tid << 2) + (m & 3);
        ((unsigned char*)idxb)[j] = (unsigned char)(idx + 1);
        lst[idx] = make_int2(j, (int)bits);
      }
      if (key == Bs) {
        int c = atomicAdd(&candn, 1);
        if (c < CCAP) cand[c] = bits;
      }
    }
  }
  __syncthreads();                                  // barrier 3
  const int na = lcount < LCAP ? lcount : LCAP;

  // ---- phase 4: per-wave redundant rank of (KSEL-cb)-th inside boundary bin ----
  unsigned thrb;
  {
    int found = 0; unsigned fv = 0;
    const int Krem = KSEL - cb;
    if (candn <= CCAP) {                            // normal: nc tiny (~1-4)
      int nc = candn;
      if (lane < nc) {
        unsigned v = cand[lane];
        int lt = 0, le = 0;
        for (int m = 0; m < nc; ++m) { unsigned u = cand[m]; lt += (u < v); le += (u <= v); }
        if (lt < Krem && le >= Krem) { found = 1; fv = v; }
      }
    } else {                                        // overflow (~never): rank whole list
      for (int e = lane; e < na; e += 64) {
        unsigned v = (unsigned)lst[e].y;
        int lt = 0, le = 0;
        for (int m = 0; m < na; ++m) {
          unsigned u = (unsigned)lst[m].y;
          lt += (u < v); le += (u <= v);
        }
        if (lt < KSEL && le >= KSEL) { found = 1; fv = v; }
      }
    }
    unsigned long long mk = __ballot(found != 0);
    unsigned d24 = (unsigned)__shfl((int)fv, __ffsll((long long)mk) - 1);
    thrb = d24 > RADB ? d24 : RADB;
  }

  // ---- phase 5: scores (thread tid owns list entry tid) -> packed (j, score) ----
  const float* tdb = tdT ? tdT + (size_t)b * NN * CD : nullptr;
  if (tid < na) {
    int2 en = lst[tid];
    int j = en.x;
    unsigned bits = (unsigned)en.y;
    float d2 = __uint_as_float(bits);
    float a0 = 0.f, a1 = 0.f, a2 = 0.f, a3 = 0.f;
    if (tdb) {
      const float4* trow = (const float4*)(tdb + (size_t)j * CD);
#pragma unroll
      for (int q = 0; q < CD / 4; q += 4) {
        float4 x0 = sdp4[q],     t0 = trow[q];
        float4 x1 = sdp4[q + 1], t1 = trow[q + 1];
        float4 x2 = sdp4[q + 2], t2 = trow[q + 2];
        float4 x3 = sdp4[q + 3], t3 = trow[q + 3];
        a0 = fmaf(x0.x, t0.x, fmaf(x0.y, t0.y, fmaf(x0.z, t0.z, fmaf(x0.w, t0.w, a0))));
        a1 = fmaf(x1.x, t1.x, fmaf(x1.y, t1.y, fmaf(x1.z, t1.z, fmaf(x1.w, t1.w, a1))));
        a2 = fmaf(x2.x, t2.x, fmaf(x2.y, t2.y, fmaf(x2.z, t2.z, fmaf(x2.w, t2.w, a2))));
        a3 = fmaf(x3.x, t3.x, fmaf(x3.y, t3.y, fmaf(x3.z, t3.z, fmaf(x3.w, t3.w, a3))));
      }
    } else {
      const float* spx = (const float*)sdp4;
      const float* tp  = td + (size_t)b * CD * NN + j;
#pragma unroll 8
      for (int c2 = 0; c2 < CD; ++c2) a0 = fmaf(spx[c2], tp[(size_t)c2 * NN], a0);
    }
    float sim = (a0 + a1) + (a2 + a3);
    float aj;
    if (addj) {
      aj = addj[(size_t)b * NN + j];
    } else {
      float l0 = tml[(size_t)b * 2 * NN + j];
      float l1 = tml[(size_t)b * 2 * NN + NN + j];
      float x  = l1 - l0;
      float sp = fmaxf(x, 0.0f) + log1pf(expf(-fabsf(x)));
      aj = fmaxf(-sp, -20.0f) - 0.1f * tu[(size_t)b * NN + j];
    }
    // boundary-bin tail beyond the 24th: not allowed -> p must be exactly 0
    float sco = (bits <= thrb) ? (sim - sqrtf(d2) + aj) : -1e30f;
    slist[tid] = make_int2(j, __float_as_int(sco));
  }
  __syncthreads();                                  // barrier 4 (last)

  // ---- phase 6: per-wave redundant softmax + fused stats (b64 reads) ----
  const float C1   = (1.0f / 0.07f) * 1.44269504089f;  // log2(e)/TEMP
  const float STEP = 2.0f / 15.0f;
  const float LN2  = 0.69314718056f;
  float m_ = -1e30f;
  for (int e = lane; e < na; e += 64) m_ = fmaxf(m_, __int_as_float(slist[e].y));
#pragma unroll
  for (int off = 32; off; off >>= 1) m_ = fmaxf(m_, __shfl_xor(m_, off));
  float zl = 0.f, eu = 0.f, e0 = 0.f, e1 = 0.f, e2 = 0.f;
  for (int e = lane; e < na; e += 64) {
    int2 sv = slist[e];
    float u  = (__int_as_float(sv.y) - m_) * C1;
    float ev = exp2f(u);
    int j = sv.x;
    float pz = -1.0f + STEP * (float)(j >> 8);
    float py = -1.0f + STEP * (float)((j >> 4) & 15);
    float px = -1.0f + STEP * (float)(j & 15);
    zl += ev; eu = fmaf(ev, u, eu);
    e0 = fmaf(ev, pz, e0); e1 = fmaf(ev, py, e1); e2 = fmaf(ev, px, e2);
  }
#pragma unroll
  for (int off = 32; off; off >>= 1) {
    zl += __shfl_xor(zl, off); eu += __shfl_xor(eu, off);
    e0 += __shfl_xor(e0, off); e1 += __shfl_xor(e1, off); e2 += __shfl_xor(e2, off);
  }
  const float invZ = 1.0f / zl;   // note: max(probs) == invZ exactly (top ev == 1)

  // ---- phase 7: expand + NT row write ----
  f4v* prow4 = (f4v*)(oprob + (size_t)row * NN);
#pragma unroll
  for (int q = 0; q < 4; ++q) {
    int c = (q << 8) + tid;
    unsigned pk = idxb[c];
    f4v v; v[0] = 0.f; v[1] = 0.f; v[2] = 0.f; v[3] = 0.f;
    if (pk) {
#pragma unroll
      for (int r = 0; r < 4; ++r) {
        unsigned u8 = (pk >> (8 * r)) & 0xFFu;
        if (u8) v[r] = exp2f((__int_as_float(slist[u8 - 1].y) - m_) * C1) * invZ;
      }
    }
    __builtin_nontemporal_store(v, &prow4[c]);
  }

  // ---- epilogue (tid 0 holds wave-0's redundant stats) ----
  if (tid == 0) {
    float p0 = e0 * invZ, p1 = e1 * invZ, p2 = e2 * invZ;
    float ent = LN2 * (log2f(zl) - eu * invZ);
    float tz = -1.0f + STEP * (float)(i >> 8);
    float ty = -1.0f + STEP * (float)((i >> 4) & 15);
    float tx = -1.0f + STEP * (float)(i & 15);
    size_t r3 = (size_t)row * 3;
    oexp[r3 + 0] = p0; oexp[r3 + 1] = p1; oexp[r3 + 2] = p2;
    osrc[r3 + 0] = tz; osrc[r3 + 1] = ty; osrc[r3 + 2] = tx;
    size_t db = (size_t)b * 3 * NN;
    odisp[db + 0 * NN + i] = p0 - tz;
    odisp[db + 1 * NN + i] = p1 - ty;
    odisp[db + 2 * NN + i] = p2 - tx;
    float ls0 = sml[(size_t)b * 2 * NN + i];
    float ls1 = sml[(size_t)b * 2 * NN + NN + i];
    float smv = 1.0f / (1.0f + expf(ls1 - ls0));
    oconf[(size_t)b * NN + i] = invZ * smv;
    oent[(size_t)b * NN + i]  = ent;
  }
}

extern "C" void kernel_launch(void* const* d_in, const int* in_sizes, int n_in,
                              void* d_out, int out_size, void* d_ws, size_t ws_size,
                              hipStream_t stream) {
  const float* sc  = (const float*)d_in[0];
  const float* tc  = (const float*)d_in[1];
  const float* sd  = (const float*)d_in[2];
  const float* td  = (const float*)d_in[3];
  const float* sml = (const float*)d_in[4];
  const float* tml = (const float*)d_in[5];
  const float* tu  = (const float*)d_in[7];
  // src_unc (d_in[6]) cancels in the row softmax -> unused

  float* out   = (float*)d_out;
  float* oexp  = out;
  float* odisp = oexp  + (size_t)BATCH * NN * 3;
  float* oprob = odisp + (size_t)BATCH * NN * 3;
  float* oconf = oprob + (size_t)BATCH * NN * NN;
  float* oent  = oconf + (size_t)BATCH * NN;
  float* osrc  = oent  + (size_t)BATCH * NN;

  size_t need = ((size_t)2 * BATCH * NN * CD + (size_t)BATCH * NN) * sizeof(float);
  float* tdT = nullptr; float* sdT = nullptr; float* adj = nullptr;
  if (ws_size >= need) {
    tdT = (float*)d_ws;
    sdT = tdT + (size_t)BATCH * NN * CD;
    adj = sdT + (size_t)BATCH * NN * CD;
    prep_all<<<256 + 32, 256, 0, stream>>>(td, sd, tml, tu, tdT, sdT, adj);
  }
  matcher_main<<<BATCH * NN, 256, 0, stream>>>(sc, tc, sd, td, tdT, sdT, adj,
                                               tml, tu, sml,
                                               oexp, odisp, oprob, oconf, oent, osrc);
}